// Round 8
// baseline (1615.679 us; speedup 1.0000x reference)
//
#include <hip/hip_runtime.h>

typedef _Float16 half2f __attribute__((ext_vector_type(2)));
typedef _Float16 half8  __attribute__((ext_vector_type(8)));
typedef float    floatx4 __attribute__((ext_vector_type(4)));

#define HID 128   // hidden size
#define G4  512   // 4*HID
#define DIN 64    // input dim

__device__ __forceinline__ float fdot2(half2f a, half2f b, float c) {
  return __builtin_amdgcn_fdot2(a, b, c, false);
}
__device__ __forceinline__ half2f as_h2(unsigned int u) {
  return __builtin_bit_cast(half2f, u);
}
__device__ __forceinline__ half2f mk2(float a, float b) {
  half2f r; r.x = (_Float16)a; r.y = (_Float16)b; return r;
}
__device__ __forceinline__ half8 cvt8(float4 a, float4 b) {
  half8 r;
  r[0] = (_Float16)a.x; r[1] = (_Float16)a.y;
  r[2] = (_Float16)a.z; r[3] = (_Float16)a.w;
  r[4] = (_Float16)b.x; r[5] = (_Float16)b.y;
  r[6] = (_Float16)b.z; r[7] = (_Float16)b.w;
  return r;
}
__device__ __forceinline__ float sigmoidf_fast(float x) {
  return __builtin_amdgcn_rcpf(1.0f + __expf(-x));
}
__device__ __forceinline__ float tanhf_fast(float x) {
  return 2.0f * __builtin_amdgcn_rcpf(1.0f + __expf(-2.0f * x)) - 1.0f;
}
template <int CTRL>
__device__ __forceinline__ float dpp_bcast(float x) {
  int m = __builtin_amdgcn_update_dpp(0, __builtin_bit_cast(int, x),
                                      CTRL, 0xF, 0xF, true);
  return __builtin_bit_cast(float, m);
}
#define QP_B0 0x00
#define QP_B1 0x55
#define QP_B2 0xAA
#define QP_B3 0xFF

// Barrier that does NOT drain vmcnt (prefetch loads stay in flight).
__device__ __forceinline__ void barrier_lgkm() {
  asm volatile("s_waitcnt lgkmcnt(0)" ::: "memory");
  __builtin_amdgcn_s_barrier();
  asm volatile("" ::: "memory");
}

// ---------------------------------------------------------------------------
// Phase 1: x_proj (+bias), fp16, stored in the scan's MFMA-blocked layout.
// G = unit*4 + gate (permuted). fp16 index within a timestep row:
//   sidx = (G>>6)*64 + (G&15)*4 + ((G>>4)&3)
// so scan wave w, lane l reads ONE uint2 (4 fp16 = its 4 tiles at col l&15).
// ---------------------------------------------------------------------------
__global__ __launch_bounds__(512, 2)
void xproj_kernel(const float* __restrict__ x, const float* __restrict__ Wih,
                  const float* __restrict__ bih, const float* __restrict__ bhh,
                  _Float16* __restrict__ xp, int nrows)
{
  const int gp   = threadIdx.x;          // permuted gate index G
  const int unit = gp >> 2;
  const int gate = gp & 3;
  const int row  = gate * HID + unit;    // row in W_ih / bias
  const int sidx = ((gp >> 6) << 6) + ((gp & 15) << 2) + ((gp >> 4) & 3);

  half2f wi[32];
  {
    const float4* wr = (const float4*)(Wih + (size_t)row * DIN);
#pragma unroll
    for (int q = 0; q < 16; q++) {
      float4 v = wr[q];
      wi[2 * q + 0] = mk2(v.x, v.y);
      wi[2 * q + 1] = mk2(v.z, v.w);
    }
  }
  const float bias = bih[row] + bhh[row];

  __shared__ __align__(16) _Float16 xin[8 * DIN];

  const int rows_per_block = (nrows + (int)gridDim.x - 1) / (int)gridDim.x;
  const int r0 = blockIdx.x * rows_per_block;
  const int r1 = (r0 + rows_per_block < nrows) ? (r0 + rows_per_block) : nrows;

  const int rsub = threadIdx.x >> 6;  // 0..7
  const int dd   = threadIdx.x & 63;

  float vld = 0.f;
  if (r0 + rsub < nrows) vld = x[(size_t)(r0 + rsub) * DIN + dd];

  for (int r = r0; r < r1; r += 8) {
    barrier_lgkm();
    xin[rsub * DIN + dd] = (_Float16)vld;
    barrier_lgkm();
    int rn = r + 8 + rsub;
    if (rn < nrows) vld = x[(size_t)rn * DIN + dd];

    const uint4* xi4 = (const uint4*)xin;
#pragma unroll
    for (int k = 0; k < 8; k++) {
      if (r + k >= r1) break;
      const uint4* rowp = xi4 + k * (DIN / 8);
      float a[4] = {bias, 0.f, 0.f, 0.f};
#pragma unroll
      for (int q = 0; q < 8; q++) {
        uint4 hv = rowp[q];
        a[q & 3] = fdot2(as_h2(hv.x), wi[4 * q + 0], a[q & 3]);
        a[q & 3] = fdot2(as_h2(hv.y), wi[4 * q + 1], a[q & 3]);
        a[q & 3] = fdot2(as_h2(hv.z), wi[4 * q + 2], a[q & 3]);
        a[q & 3] = fdot2(as_h2(hv.w), wi[4 * q + 3], a[q & 3]);
      }
      xp[(size_t)(r + k) * G4 + sidx] = (_Float16)(a[0] + a[1] + a[2] + a[3]);
    }
  }
}

// ---------------------------------------------------------------------------
// Phase 2: MFMA scan. 64 blocks x 512 threads (8 waves, 2/SIMD).
// gates(512) = Whh(512x128) . h(128) via mfma_f32_16x16x32_f16 with ALL 16
// rows of A = h  =>  D[m][n] = gate[n] in EVERY lane/reg (layout-robust,
// HW-verified round 7). Wave w owns 4 N-tiles (64 permuted gates).
// B-frags = 4x4x half8 = 64 VGPRs -> fully register-resident at 2 waves/SIMD.
// acc C-operand carries x-projection (+bias). Lane activates its own gate
// type (gt = col&3) for all 4 tiles; quad-DPP regathers i,f,g,o; c,h
// replicated per quad. One LDS round-trip + one lgkm-only barrier per step.
// ---------------------------------------------------------------------------
__global__ __launch_bounds__(512, 2)
void lstm_scan7(const float* __restrict__ Whh,
                const float* __restrict__ h0, const float* __restrict__ c0,
                const _Float16* __restrict__ xp,
                float* __restrict__ out, int T)
{
  const int tid  = threadIdx.x;
  const int w    = tid >> 6;   // wave 0..7
  const int lane = tid & 63;
  const int s    = lane >> 4;  // 0..3 (K-slot group)
  const int col  = lane & 15;
  const int gt   = col & 3;    // gate type of this lane's columns
  const int cq   = col >> 2;   // quad index within the 16 cols
  const int b    = blockIdx.x;

  // B-fragments: tile ti x chunk kc; lane slot j holds
  // Whh[rowOf(G)][kc*32 + s*8 + j]  (same (s,j)->k map as the A-frag).
  half8 bfr[4][4];
#pragma unroll
  for (int ti = 0; ti < 4; ti++) {
    const int G    = (w * 4 + ti) * 16 + col;   // permuted gate index
    const int unit = G >> 2;
    const int g_   = G & 3;
    const float* wrow = Whh + (size_t)(g_ * HID + unit) * HID;
#pragma unroll
    for (int kc = 0; kc < 4; kc++) {
      const float4* p = (const float4*)(wrow + kc * 32 + s * 8);
      bfr[ti][kc] = cvt8(p[0], p[1]);
    }
  }

  // activation constants: act = mm*rcp(1+exp(kk*x)) + bb  (sigmoid / tanh)
  const float kk = (gt == 2) ? -2.f : -1.f;
  const float mm = (gt == 2) ?  2.f :  1.f;
  const float bb = (gt == 2) ? -1.f :  0.f;

  __shared__ __align__(16) _Float16 h_sh[2][HID];

  // my 4 units (one per tile): u(ti) = w*16 + ti*4 + cq
  float c[4];
#pragma unroll
  for (int ti = 0; ti < 4; ti++)
    c[ti] = c0[(size_t)b * HID + (w * 16 + ti * 4 + cq)];
  if (tid < HID) h_sh[0][tid] = (_Float16)h0[(size_t)b * HID + tid];

  // xp: one uint2 (4 fp16, one per tile at my col) per step
  const uint2* xp2 = (const uint2*)xp;
  const size_t xbase = (size_t)b * T * (G4 / 4) + w * 16 + col;
  uint2 xq  = xp2[xbase];
  uint2 xq1 = (T > 1) ? xp2[xbase + (G4 / 4)] : xq;

  barrier_lgkm();

  const _Float16* rb = h_sh[0];
  _Float16*       wb = h_sh[1];

  for (int t = 0; t < T; ++t) {
    uint2 xq2 = xq1;
    if (t + 2 < T) xq2 = xp2[xbase + (size_t)(t + 2) * (G4 / 4)];

    // A-fragments: every lane loads h[kc*32 + s*8 .. +7] (all rows = h)
    const uint4* h4 = (const uint4*)rb;
    half8 af0 = __builtin_bit_cast(half8, h4[0 * 4 + s]);
    half8 af1 = __builtin_bit_cast(half8, h4[1 * 4 + s]);
    half8 af2 = __builtin_bit_cast(half8, h4[2 * 4 + s]);
    half8 af3 = __builtin_bit_cast(half8, h4[3 * 4 + s]);

    // acc init = xp (C-operand): all 4 regs = xp[tile][col]
    floatx4 acc[4];
    {
      half8 xh = __builtin_bit_cast(half8, (uint4){xq.x, xq.y, xq.x, xq.y});
#pragma unroll
      for (int ti = 0; ti < 4; ti++) {
        float xv = (float)xh[ti];
        acc[ti] = (floatx4){xv, xv, xv, xv};
      }
    }

#pragma unroll
    for (int ti = 0; ti < 4; ti++)
      acc[ti] = __builtin_amdgcn_mfma_f32_16x16x32_f16(af0, bfr[ti][0], acc[ti], 0, 0, 0);
#pragma unroll
    for (int ti = 0; ti < 4; ti++)
      acc[ti] = __builtin_amdgcn_mfma_f32_16x16x32_f16(af1, bfr[ti][1], acc[ti], 0, 0, 0);
#pragma unroll
    for (int ti = 0; ti < 4; ti++)
      acc[ti] = __builtin_amdgcn_mfma_f32_16x16x32_f16(af2, bfr[ti][2], acc[ti], 0, 0, 0);
#pragma unroll
    for (int ti = 0; ti < 4; ti++)
      acc[ti] = __builtin_amdgcn_mfma_f32_16x16x32_f16(af3, bfr[ti][3], acc[ti], 0, 0, 0);

    // per tile: activate own gate type, quad-regather i,f,g,o, update c,h
    float hval[4];
#pragma unroll
    for (int ti = 0; ti < 4; ti++) {
      float v   = acc[ti][0];
      float act = fmaf(mm, __builtin_amdgcn_rcpf(1.0f + __expf(kk * v)), bb);
      float gi = dpp_bcast<QP_B0>(act);
      float gf = dpp_bcast<QP_B1>(act);
      float gg = dpp_bcast<QP_B2>(act);
      float go = dpp_bcast<QP_B3>(act);
      c[ti] = fmaf(gf, c[ti], gi * gg);
      hval[ti] = go * tanhf_fast(c[ti]);
    }

    if (gt == 0) {
#pragma unroll
      for (int ti = 0; ti < 4; ti++)
        wb[w * 16 + ti * 4 + cq] = (_Float16)hval[ti];
    } else if (gt == 1) {
      const size_t obase = ((size_t)b * T + t) * HID;
#pragma unroll
      for (int ti = 0; ti < 4; ti++)
        out[obase + (w * 16 + ti * 4 + cq)] = hval[ti];
    }

    barrier_lgkm();                     // vmcnt NOT drained
    const _Float16* tmp = rb; rb = wb; wb = (_Float16*)tmp;
    xq = xq1; xq1 = xq2;
  }
}

// ---------------------------------------------------------------------------
// Fallback (ws too small): inline x-proj, round-1 structure.
// ---------------------------------------------------------------------------
__global__ __launch_bounds__(512, 2)
void lstm_scan_fb(const float* __restrict__ x, const float* __restrict__ Wih,
                  const float* __restrict__ Whh,
                  const float* __restrict__ bih, const float* __restrict__ bhh,
                  const float* __restrict__ h0, const float* __restrict__ c0,
                  float* __restrict__ out, int T)
{
  const int g = threadIdx.x;
  const int b = blockIdx.x;

  half2f w[64];
  {
    const float4* wr = (const float4*)(Whh + (size_t)g * HID);
#pragma unroll
    for (int q = 0; q < 32; q++) {
      float4 v = wr[q];
      w[2 * q + 0] = mk2(v.x, v.y);
      w[2 * q + 1] = mk2(v.z, v.w);
    }
  }
  half2f wi[32];
  float bias;
  {
    const float4* wr = (const float4*)(Wih + (size_t)g * DIN);
#pragma unroll
    for (int q = 0; q < 16; q++) {
      float4 v = wr[q];
      wi[2 * q + 0] = mk2(v.x, v.y);
      wi[2 * q + 1] = mk2(v.z, v.w);
    }
    bias = bih[g] + bhh[g];
  }

  __shared__ __align__(16) _Float16 h_sh[HID];
  __shared__ __align__(16) _Float16 xin[DIN];
  __shared__ float pre[G4];

  float c = 0.f;
  if (g < HID) {
    c = c0[(size_t)b * HID + g];
    h_sh[g] = (_Float16)h0[(size_t)b * HID + g];
  }
  if (g < DIN) xin[g] = (_Float16)x[((size_t)b * T) * DIN + g];
  __syncthreads();

  const bool is_tanh_gate = (g >= 2 * HID) && (g < 3 * HID);

  for (int t = 0; t < T; ++t) {
    float a[4] = {0.f, 0.f, 0.f, 0.f};
    const uint4* h4 = (const uint4*)h_sh;
#pragma unroll
    for (int q = 0; q < 16; q++) {
      uint4 hv = h4[q];
      a[q & 3] = fdot2(as_h2(hv.x), w[4 * q + 0], a[q & 3]);
      a[q & 3] = fdot2(as_h2(hv.y), w[4 * q + 1], a[q & 3]);
      a[q & 3] = fdot2(as_h2(hv.z), w[4 * q + 2], a[q & 3]);
      a[q & 3] = fdot2(as_h2(hv.w), w[4 * q + 3], a[q & 3]);
    }
    const uint4* x4 = (const uint4*)xin;
#pragma unroll
    for (int q = 0; q < 8; q++) {
      uint4 hv = x4[q];
      a[q & 3] = fdot2(as_h2(hv.x), wi[4 * q + 0], a[q & 3]);
      a[q & 3] = fdot2(as_h2(hv.y), wi[4 * q + 1], a[q & 3]);
      a[q & 3] = fdot2(as_h2(hv.z), wi[4 * q + 2], a[q & 3]);
      a[q & 3] = fdot2(as_h2(hv.w), wi[4 * q + 3], a[q & 3]);
    }
    float preact = a[0] + a[1] + a[2] + a[3] + bias;
    float act = is_tanh_gate ? tanhf_fast(preact) : sigmoidf_fast(preact);
    pre[g] = act;
    __syncthreads();

    if (g < HID) {
      float i  = pre[g];
      float f  = pre[g + HID];
      float gg = pre[g + 2 * HID];
      float o  = pre[g + 3 * HID];
      c = f * c + i * gg;
      float h = o * tanhf_fast(c);
      out[((size_t)b * T + t) * HID + g] = h;
      h_sh[g] = (_Float16)h;
    } else if (g >= HID && g < HID + DIN) {
      int d = g - HID;
      if (t + 1 < T) xin[d] = (_Float16)x[((size_t)b * T + (t + 1)) * DIN + d];
    }
    __syncthreads();
  }
}

// ---------------------------------------------------------------------------
extern "C" void kernel_launch(void* const* d_in, const int* in_sizes, int n_in,
                              void* d_out, int out_size, void* d_ws, size_t ws_size,
                              hipStream_t stream)
{
  const float* x   = (const float*)d_in[0];
  const float* Wih = (const float*)d_in[1];
  const float* Whh = (const float*)d_in[2];
  const float* bih = (const float*)d_in[3];
  const float* bhh = (const float*)d_in[4];
  const float* h0  = (const float*)d_in[5];
  const float* c0  = (const float*)d_in[6];
  float* out = (float*)d_out;

  const int B = in_sizes[5] / HID;
  const int T = in_sizes[0] / (B * DIN);
  const int nrows = B * T;

  const size_t xp_bytes = (size_t)nrows * G4 * sizeof(_Float16);
  if (ws_size >= xp_bytes) {
    _Float16* xp = (_Float16*)d_ws;
    xproj_kernel<<<1024, 512, 0, stream>>>(x, Wih, bih, bhh, xp, nrows);
    lstm_scan7<<<B, 512, 0, stream>>>(Whh, h0, c0, xp, out, T);
  } else {
    lstm_scan_fb<<<B, 512, 0, stream>>>(x, Wih, Whh, bih, bhh, h0, c0, out, T);
  }
}

// Round 9
// 1188.509 us; speedup vs baseline: 1.3594x; 1.3594x over previous
//
#include <hip/hip_runtime.h>

typedef _Float16 half2f __attribute__((ext_vector_type(2)));

#define HID 128   // hidden size
#define G4  512   // 4*HID
#define DIN 64    // input dim

__device__ __forceinline__ float fdot2(half2f a, half2f b, float c) {
  return __builtin_amdgcn_fdot2(a, b, c, false);
}
__device__ __forceinline__ half2f as_h2(unsigned int u) {
  return __builtin_bit_cast(half2f, u);
}
__device__ __forceinline__ half2f mk2(float a, float b) {
  half2f r; r.x = (_Float16)a; r.y = (_Float16)b; return r;
}
__device__ __forceinline__ float sigmoidf_fast(float x) {
  return __builtin_amdgcn_rcpf(1.0f + __expf(-x));
}
__device__ __forceinline__ float tanhf_fast(float x) {
  return 2.0f * __builtin_amdgcn_rcpf(1.0f + __expf(-2.0f * x)) - 1.0f;
}
template <int CTRL>
__device__ __forceinline__ float dpp_add(float x) {
  int m = __builtin_amdgcn_update_dpp(0, __builtin_bit_cast(int, x),
                                      CTRL, 0xF, 0xF, true);
  return x + __builtin_bit_cast(float, m);
}
template <int CTRL>
__device__ __forceinline__ float dpp_bcast(float x) {
  int m = __builtin_amdgcn_update_dpp(0, __builtin_bit_cast(int, x),
                                      CTRL, 0xF, 0xF, true);
  return __builtin_bit_cast(float, m);
}
#define QP_XOR1 0xB1  // [1,0,3,2]
#define QP_XOR2 0x4E  // [2,3,0,1]
#define QP_B0   0x00
#define QP_B1   0x55
#define QP_B2   0xAA
#define QP_B3   0xFF

// Barrier that does NOT drain vmcnt (prefetch loads stay in flight).
__device__ __forceinline__ void barrier_lgkm() {
  asm volatile("s_waitcnt lgkmcnt(0)" ::: "memory");
  __builtin_amdgcn_s_barrier();
  asm volatile("" ::: "memory");
}

// ---------------------------------------------------------------------------
// Phase 1: x_proj (+bias), fp16, stored PERMUTED: [r][unit*4 + gate].
// Scan thread tid = j*4+q reads the single fp16 at [r][tid].
// ---------------------------------------------------------------------------
__global__ __launch_bounds__(512, 2)
void xproj_kernel(const float* __restrict__ x, const float* __restrict__ Wih,
                  const float* __restrict__ bih, const float* __restrict__ bhh,
                  _Float16* __restrict__ xp, int nrows)
{
  const int gp   = threadIdx.x;          // permuted gate index
  const int unit = gp >> 2;
  const int gate = gp & 3;
  const int row  = gate * HID + unit;    // row in W_ih / bias

  half2f wi[32];
  {
    const float4* wr = (const float4*)(Wih + (size_t)row * DIN);
#pragma unroll
    for (int q = 0; q < 16; q++) {
      float4 v = wr[q];
      wi[2 * q + 0] = mk2(v.x, v.y);
      wi[2 * q + 1] = mk2(v.z, v.w);
    }
  }
  const float bias = bih[row] + bhh[row];

  __shared__ __align__(16) _Float16 xin[8 * DIN];

  const int rows_per_block = (nrows + (int)gridDim.x - 1) / (int)gridDim.x;
  const int r0 = blockIdx.x * rows_per_block;
  const int r1 = (r0 + rows_per_block < nrows) ? (r0 + rows_per_block) : nrows;

  const int rsub = threadIdx.x >> 6;  // 0..7
  const int dd   = threadIdx.x & 63;

  float vld = 0.f;
  if (r0 + rsub < nrows) vld = x[(size_t)(r0 + rsub) * DIN + dd];

  for (int r = r0; r < r1; r += 8) {
    barrier_lgkm();
    xin[rsub * DIN + dd] = (_Float16)vld;
    barrier_lgkm();
    int rn = r + 8 + rsub;
    if (rn < nrows) vld = x[(size_t)rn * DIN + dd];

    const uint4* xi4 = (const uint4*)xin;
#pragma unroll
    for (int k = 0; k < 8; k++) {
      if (r + k >= r1) break;
      const uint4* rowp = xi4 + k * (DIN / 8);
      float a[4] = {bias, 0.f, 0.f, 0.f};
#pragma unroll
      for (int q = 0; q < 8; q++) {
        uint4 hv = rowp[q];
        a[q & 3] = fdot2(as_h2(hv.x), wi[4 * q + 0], a[q & 3]);
        a[q & 3] = fdot2(as_h2(hv.y), wi[4 * q + 1], a[q & 3]);
        a[q & 3] = fdot2(as_h2(hv.z), wi[4 * q + 2], a[q & 3]);
        a[q & 3] = fdot2(as_h2(hv.w), wi[4 * q + 3], a[q & 3]);
      }
      xp[(size_t)(r + k) * G4 + gp] = (_Float16)(a[0] + a[1] + a[2] + a[3]);
    }
  }
}

// ---------------------------------------------------------------------------
// Phase 2: scan. 64 blocks x 512 threads (8 waves, 2 waves/SIMD).
// Thread (j = tid>>2, q = tid&3): 4 gates of unit j over K-quarter q
// (32 h elems -> 64 fdot2/thread). Weights in FOUR NAMED arrays w0..w3[16]
// (round-2/5 proven register-resident style; round-3's 2D array demoted).
// Quad = unit: DPP xor1+xor2 reduces K-partials; per-lane branchless
// activation of own gate type; quad-broadcast regather; c replicated per
// quad. One LDS roundtrip + one lgkm-only barrier per step; xp prefetch
// depth 2 stays in flight across barriers.
// ---------------------------------------------------------------------------
__global__ __launch_bounds__(512, 2)
void lstm_scan8(const float* __restrict__ Whh,
                const float* __restrict__ h0, const float* __restrict__ c0,
                const _Float16* __restrict__ xp,
                float* __restrict__ out, int T)
{
  const int tid = threadIdx.x;
  const int j   = tid >> 2;
  const int q   = tid & 3;
  const int b   = blockIdx.x;

  // W_hh rows gate*128+j, cols [32q, 32q+32) -> 16 half2 per gate
  half2f w0[16], w1[16], w2[16], w3[16];
  {
    const float4* r0 = (const float4*)(Whh + ((size_t)(0 * HID + j)) * HID + q * 32);
    const float4* r1 = (const float4*)(Whh + ((size_t)(1 * HID + j)) * HID + q * 32);
    const float4* r2 = (const float4*)(Whh + ((size_t)(2 * HID + j)) * HID + q * 32);
    const float4* r3 = (const float4*)(Whh + ((size_t)(3 * HID + j)) * HID + q * 32);
#pragma unroll
    for (int p = 0; p < 8; p++) {
      float4 v;
      v = r0[p]; w0[2 * p] = mk2(v.x, v.y); w0[2 * p + 1] = mk2(v.z, v.w);
      v = r1[p]; w1[2 * p] = mk2(v.x, v.y); w1[2 * p + 1] = mk2(v.z, v.w);
      v = r2[p]; w2[2 * p] = mk2(v.x, v.y); w2[2 * p + 1] = mk2(v.z, v.w);
      v = r3[p]; w3[2 * p] = mk2(v.x, v.y); w3[2 * p + 1] = mk2(v.z, v.w);
    }
  }

  // hoisted per-lane constants
  const float s0 = (q == 0) ? 1.f : 0.f;
  const float s1 = (q == 1) ? 1.f : 0.f;
  const float s2 = (q == 2) ? 1.f : 0.f;
  const float s3 = (q == 3) ? 1.f : 0.f;
  const float kk = (q == 2) ? -2.f : -1.f;   // tanh gate
  const float mm = (q == 2) ?  2.f :  1.f;
  const float bb = (q == 2) ? -1.f :  0.f;

  __shared__ __align__(16) _Float16 h_sh[2][HID];

  float c = c0[(size_t)b * HID + j];
  if (q == 0) h_sh[0][j] = (_Float16)h0[(size_t)b * HID + j];
  __syncthreads();

  // xp: one fp16 per thread per step at [t][j*4+q] = [t][tid]
  const unsigned short* xps = (const unsigned short*)xp;
  const size_t xbase = (size_t)b * T * G4 + tid;
  unsigned short xv  = xps[xbase];
  unsigned short xv1 = (T > 1) ? xps[xbase + G4] : (unsigned short)0;

  const _Float16* rb = h_sh[0];
  _Float16*       wb = h_sh[1];

  for (int t = 0; t < T; ++t) {
    unsigned short xv2 = 0;
    if (t + 2 < T) xv2 = xps[xbase + (size_t)(t + 2) * G4];

    // my K-quarter of h: 4x ds_read_b128, all in flight
    uint4 hv0, hv1, hv2, hv3;
    {
      const uint4* h4 = (const uint4*)(rb + q * 32);
      hv0 = h4[0]; hv1 = h4[1]; hv2 = h4[2]; hv3 = h4[3];
    }

    float a0 = 0.f, a1 = 0.f, a2 = 0.f, a3 = 0.f;
#define DOTQ(vv, base)                                          \
    do {                                                        \
      a0 = fdot2(as_h2((vv).x), w0[(base) + 0], a0);            \
      a1 = fdot2(as_h2((vv).x), w1[(base) + 0], a1);            \
      a2 = fdot2(as_h2((vv).x), w2[(base) + 0], a2);            \
      a3 = fdot2(as_h2((vv).x), w3[(base) + 0], a3);            \
      a0 = fdot2(as_h2((vv).y), w0[(base) + 1], a0);            \
      a1 = fdot2(as_h2((vv).y), w1[(base) + 1], a1);            \
      a2 = fdot2(as_h2((vv).y), w2[(base) + 1], a2);            \
      a3 = fdot2(as_h2((vv).y), w3[(base) + 1], a3);            \
      a0 = fdot2(as_h2((vv).z), w0[(base) + 2], a0);            \
      a1 = fdot2(as_h2((vv).z), w1[(base) + 2], a1);            \
      a2 = fdot2(as_h2((vv).z), w2[(base) + 2], a2);            \
      a3 = fdot2(as_h2((vv).z), w3[(base) + 2], a3);            \
      a0 = fdot2(as_h2((vv).w), w0[(base) + 3], a0);            \
      a1 = fdot2(as_h2((vv).w), w1[(base) + 3], a1);            \
      a2 = fdot2(as_h2((vv).w), w2[(base) + 3], a2);            \
      a3 = fdot2(as_h2((vv).w), w3[(base) + 3], a3);            \
    } while (0)
    DOTQ(hv0, 0);
    DOTQ(hv1, 4);
    DOTQ(hv2, 8);
    DOTQ(hv3, 12);
#undef DOTQ

    // add x_proj: lane q carries gate q's xp (selector consts hoisted)
    {
      _Float16 xh = __builtin_bit_cast(_Float16, xv);
      float xvf = (float)xh;
      a0 = fmaf(xvf, s0, a0);
      a1 = fmaf(xvf, s1, a1);
      a2 = fmaf(xvf, s2, a2);
      a3 = fmaf(xvf, s3, a3);
    }

    // quad reduction over K-quarters (VALU-only)
    a0 = dpp_add<QP_XOR1>(a0); a0 = dpp_add<QP_XOR2>(a0);
    a1 = dpp_add<QP_XOR1>(a1); a1 = dpp_add<QP_XOR2>(a1);
    a2 = dpp_add<QP_XOR1>(a2); a2 = dpp_add<QP_XOR2>(a2);
    a3 = dpp_add<QP_XOR1>(a3); a3 = dpp_add<QP_XOR2>(a3);

    // own-gate select (2-bit mux) + branchless activation
    float a01 = (q & 1) ? a1 : a0;
    float a23 = (q & 1) ? a3 : a2;
    float aq  = (q & 2) ? a23 : a01;
    float act = fmaf(mm, __builtin_amdgcn_rcpf(1.0f + __expf(kk * aq)), bb);

    // regather i,f,g,o within the quad
    float gi = dpp_bcast<QP_B0>(act);
    float gf = dpp_bcast<QP_B1>(act);
    float gg = dpp_bcast<QP_B2>(act);
    float go = dpp_bcast<QP_B3>(act);

    c = fmaf(gf, c, gi * gg);            // replicated per quad (bit-identical)
    float h = go * tanhf_fast(c);

    if (q == 0) wb[j] = (_Float16)h;
    if (q == 1) out[((size_t)b * T + t) * HID + j] = h;
    barrier_lgkm();                      // single barrier, vmcnt not drained
    const _Float16* tmp = rb; rb = wb; wb = (_Float16*)tmp;
    xv = xv1; xv1 = xv2;
  }
}

// ---------------------------------------------------------------------------
// Fallback (ws too small): inline x-proj, round-1 structure.
// ---------------------------------------------------------------------------
__global__ __launch_bounds__(512, 2)
void lstm_scan_fb(const float* __restrict__ x, const float* __restrict__ Wih,
                  const float* __restrict__ Whh,
                  const float* __restrict__ bih, const float* __restrict__ bhh,
                  const float* __restrict__ h0, const float* __restrict__ c0,
                  float* __restrict__ out, int T)
{
  const int g = threadIdx.x;
  const int b = blockIdx.x;

  half2f w[64];
  {
    const float4* wr = (const float4*)(Whh + (size_t)g * HID);
#pragma unroll
    for (int q = 0; q < 32; q++) {
      float4 v = wr[q];
      w[2 * q + 0] = mk2(v.x, v.y);
      w[2 * q + 1] = mk2(v.z, v.w);
    }
  }
  half2f wi[32];
  float bias;
  {
    const float4* wr = (const float4*)(Wih + (size_t)g * DIN);
#pragma unroll
    for (int q = 0; q < 16; q++) {
      float4 v = wr[q];
      wi[2 * q + 0] = mk2(v.x, v.y);
      wi[2 * q + 1] = mk2(v.z, v.w);
    }
    bias = bih[g] + bhh[g];
  }

  __shared__ __align__(16) _Float16 h_sh[HID];
  __shared__ __align__(16) _Float16 xin[DIN];
  __shared__ float pre[G4];

  float c = 0.f;
  if (g < HID) {
    c = c0[(size_t)b * HID + g];
    h_sh[g] = (_Float16)h0[(size_t)b * HID + g];
  }
  if (g < DIN) xin[g] = (_Float16)x[((size_t)b * T) * DIN + g];
  __syncthreads();

  const bool is_tanh_gate = (g >= 2 * HID) && (g < 3 * HID);

  for (int t = 0; t < T; ++t) {
    float a[4] = {0.f, 0.f, 0.f, 0.f};
    const uint4* h4 = (const uint4*)h_sh;
#pragma unroll
    for (int q = 0; q < 16; q++) {
      uint4 hv = h4[q];
      a[q & 3] = fdot2(as_h2(hv.x), w[4 * q + 0], a[q & 3]);
      a[q & 3] = fdot2(as_h2(hv.y), w[4 * q + 1], a[q & 3]);
      a[q & 3] = fdot2(as_h2(hv.z), w[4 * q + 2], a[q & 3]);
      a[q & 3] = fdot2(as_h2(hv.w), w[4 * q + 3], a[q & 3]);
    }
    const uint4* x4 = (const uint4*)xin;
#pragma unroll
    for (int q = 0; q < 8; q++) {
      uint4 hv = x4[q];
      a[q & 3] = fdot2(as_h2(hv.x), wi[4 * q + 0], a[q & 3]);
      a[q & 3] = fdot2(as_h2(hv.y), wi[4 * q + 1], a[q & 3]);
      a[q & 3] = fdot2(as_h2(hv.z), wi[4 * q + 2], a[q & 3]);
      a[q & 3] = fdot2(as_h2(hv.w), wi[4 * q + 3], a[q & 3]);
    }
    float preact = a[0] + a[1] + a[2] + a[3] + bias;
    float act = is_tanh_gate ? tanhf_fast(preact) : sigmoidf_fast(preact);
    pre[g] = act;
    __syncthreads();

    if (g < HID) {
      float i  = pre[g];
      float f  = pre[g + HID];
      float gg = pre[g + 2 * HID];
      float o  = pre[g + 3 * HID];
      c = f * c + i * gg;
      float h = o * tanhf_fast(c);
      out[((size_t)b * T + t) * HID + g] = h;
      h_sh[g] = (_Float16)h;
    } else if (g >= HID && g < HID + DIN) {
      int d = g - HID;
      if (t + 1 < T) xin[d] = (_Float16)x[((size_t)b * T + (t + 1)) * DIN + d];
    }
    __syncthreads();
  }
}

// ---------------------------------------------------------------------------
extern "C" void kernel_launch(void* const* d_in, const int* in_sizes, int n_in,
                              void* d_out, int out_size, void* d_ws, size_t ws_size,
                              hipStream_t stream)
{
  const float* x   = (const float*)d_in[0];
  const float* Wih = (const float*)d_in[1];
  const float* Whh = (const float*)d_in[2];
  const float* bih = (const float*)d_in[3];
  const float* bhh = (const float*)d_in[4];
  const float* h0  = (const float*)d_in[5];
  const float* c0  = (const float*)d_in[6];
  float* out = (float*)d_out;

  const int B = in_sizes[5] / HID;
  const int T = in_sizes[0] / (B * DIN);
  const int nrows = B * T;

  const size_t xp_bytes = (size_t)nrows * G4 * sizeof(_Float16);
  if (ws_size >= xp_bytes) {
    _Float16* xp = (_Float16*)d_ws;
    xproj_kernel<<<1024, 512, 0, stream>>>(x, Wih, bih, bhh, xp, nrows);
    lstm_scan8<<<B, 512, 0, stream>>>(Whh, h0, c0, xp, out, T);
  } else {
    lstm_scan_fb<<<B, 512, 0, stream>>>(x, Wih, Whh, bih, bhh, h0, c0, out, T);
  }
}

// Round 10
// 1188.239 us; speedup vs baseline: 1.3597x; 1.0002x over previous
//
#include <hip/hip_runtime.h>

typedef _Float16 half2f __attribute__((ext_vector_type(2)));

#define HID 128   // hidden size
#define G4  512   // 4*HID
#define DIN 64    // input dim

__device__ __forceinline__ float fdot2(half2f a, half2f b, float c) {
  return __builtin_amdgcn_fdot2(a, b, c, false);
}
__device__ __forceinline__ half2f as_h2(unsigned int u) {
  return __builtin_bit_cast(half2f, u);
}
__device__ __forceinline__ half2f mk2(float a, float b) {
  half2f r; r.x = (_Float16)a; r.y = (_Float16)b; return r;
}
__device__ __forceinline__ float sigmoidf_fast(float x) {
  return __builtin_amdgcn_rcpf(1.0f + __expf(-x));
}
__device__ __forceinline__ float tanhf_fast(float x) {
  return 2.0f * __builtin_amdgcn_rcpf(1.0f + __expf(-2.0f * x)) - 1.0f;
}
template <int CTRL>
__device__ __forceinline__ float dpp_add(float x) {
  int m = __builtin_amdgcn_update_dpp(0, __builtin_bit_cast(int, x),
                                      CTRL, 0xF, 0xF, true);
  return x + __builtin_bit_cast(float, m);
}
template <int CTRL>
__device__ __forceinline__ float dpp_bcast(float x) {
  int m = __builtin_amdgcn_update_dpp(0, __builtin_bit_cast(int, x),
                                      CTRL, 0xF, 0xF, true);
  return __builtin_bit_cast(float, m);
}
#define QP_XOR1 0xB1  // [1,0,3,2]
#define QP_XOR2 0x4E  // [2,3,0,1]
#define QP_B0   0x00
#define QP_B1   0x55
#define QP_B2   0xAA
#define QP_B3   0xFF

// Barrier that does NOT drain vmcnt (prefetch loads stay in flight).
__device__ __forceinline__ void barrier_lgkm() {
  asm volatile("s_waitcnt lgkmcnt(0)" ::: "memory");
  __builtin_amdgcn_s_barrier();
  asm volatile("" ::: "memory");
}

// ---------------------------------------------------------------------------
// Phase 1: x_proj (+bias), fp16, stored PERMUTED: [r][unit*4 + gate].
// Scan thread tid = j*4+q reads the single fp16 at [r][tid].
// ---------------------------------------------------------------------------
__global__ __launch_bounds__(512, 2)
void xproj_kernel(const float* __restrict__ x, const float* __restrict__ Wih,
                  const float* __restrict__ bih, const float* __restrict__ bhh,
                  _Float16* __restrict__ xp, int nrows)
{
  const int gp   = threadIdx.x;          // permuted gate index
  const int unit = gp >> 2;
  const int gate = gp & 3;
  const int row  = gate * HID + unit;    // row in W_ih / bias

  half2f wi[32];
  {
    const float4* wr = (const float4*)(Wih + (size_t)row * DIN);
#pragma unroll
    for (int q = 0; q < 16; q++) {
      float4 v = wr[q];
      wi[2 * q + 0] = mk2(v.x, v.y);
      wi[2 * q + 1] = mk2(v.z, v.w);
    }
  }
  const float bias = bih[row] + bhh[row];

  __shared__ __align__(16) _Float16 xin[8 * DIN];

  const int rows_per_block = (nrows + (int)gridDim.x - 1) / (int)gridDim.x;
  const int r0 = blockIdx.x * rows_per_block;
  const int r1 = (r0 + rows_per_block < nrows) ? (r0 + rows_per_block) : nrows;

  const int rsub = threadIdx.x >> 6;  // 0..7
  const int dd   = threadIdx.x & 63;

  float vld = 0.f;
  if (r0 + rsub < nrows) vld = x[(size_t)(r0 + rsub) * DIN + dd];

  for (int r = r0; r < r1; r += 8) {
    barrier_lgkm();
    xin[rsub * DIN + dd] = (_Float16)vld;
    barrier_lgkm();
    int rn = r + 8 + rsub;
    if (rn < nrows) vld = x[(size_t)rn * DIN + dd];

    const uint4* xi4 = (const uint4*)xin;
#pragma unroll
    for (int k = 0; k < 8; k++) {
      if (r + k >= r1) break;
      const uint4* rowp = xi4 + k * (DIN / 8);
      float a[4] = {bias, 0.f, 0.f, 0.f};
#pragma unroll
      for (int q = 0; q < 8; q++) {
        uint4 hv = rowp[q];
        a[q & 3] = fdot2(as_h2(hv.x), wi[4 * q + 0], a[q & 3]);
        a[q & 3] = fdot2(as_h2(hv.y), wi[4 * q + 1], a[q & 3]);
        a[q & 3] = fdot2(as_h2(hv.z), wi[4 * q + 2], a[q & 3]);
        a[q & 3] = fdot2(as_h2(hv.w), wi[4 * q + 3], a[q & 3]);
      }
      xp[(size_t)(r + k) * G4 + gp] = (_Float16)(a[0] + a[1] + a[2] + a[3]);
    }
  }
}

// ---------------------------------------------------------------------------
// Phase 2: scan. 64 blocks x 512 threads (8 waves => 2 waves/SIMD from the
// block itself; grid is 1 block/CU). Thread (j = tid>>2, q = tid&3): 4 gates
// of unit j over K-quarter q (64 fdot2/thread). Weights in four NAMED arrays.
// __launch_bounds__(512, 1): waves-per-eu=1 keeps the allocator's VGPR budget
// at 512 so the weight arrays stay register-resident (A/B vs round 9's
// (512,2) which demoted them to per-step reloads, VGPR=72).
// Quad = unit: DPP xor1+xor2 reduce; per-lane branchless activation of own
// gate; quad-broadcast regather; c replicated per quad. One LDS roundtrip +
// one lgkm-only barrier per step; xp prefetch depth 2.
// ---------------------------------------------------------------------------
__global__ __launch_bounds__(512, 1)
void lstm_scan9(const float* __restrict__ Whh,
                const float* __restrict__ h0, const float* __restrict__ c0,
                const _Float16* __restrict__ xp,
                float* __restrict__ out, int T)
{
  const int tid = threadIdx.x;
  const int j   = tid >> 2;
  const int q   = tid & 3;
  const int b   = blockIdx.x;

  // W_hh rows gate*128+j, cols [32q, 32q+32) -> 16 half2 per gate
  half2f w0[16], w1[16], w2[16], w3[16];
  {
    const float4* r0 = (const float4*)(Whh + ((size_t)(0 * HID + j)) * HID + q * 32);
    const float4* r1 = (const float4*)(Whh + ((size_t)(1 * HID + j)) * HID + q * 32);
    const float4* r2 = (const float4*)(Whh + ((size_t)(2 * HID + j)) * HID + q * 32);
    const float4* r3 = (const float4*)(Whh + ((size_t)(3 * HID + j)) * HID + q * 32);
#pragma unroll
    for (int p = 0; p < 8; p++) {
      float4 v;
      v = r0[p]; w0[2 * p] = mk2(v.x, v.y); w0[2 * p + 1] = mk2(v.z, v.w);
      v = r1[p]; w1[2 * p] = mk2(v.x, v.y); w1[2 * p + 1] = mk2(v.z, v.w);
      v = r2[p]; w2[2 * p] = mk2(v.x, v.y); w2[2 * p + 1] = mk2(v.z, v.w);
      v = r3[p]; w3[2 * p] = mk2(v.x, v.y); w3[2 * p + 1] = mk2(v.z, v.w);
    }
  }

  // hoisted per-lane constants
  const float s0 = (q == 0) ? 1.f : 0.f;
  const float s1 = (q == 1) ? 1.f : 0.f;
  const float s2 = (q == 2) ? 1.f : 0.f;
  const float s3 = (q == 3) ? 1.f : 0.f;
  const float kk = (q == 2) ? -2.f : -1.f;   // tanh gate
  const float mm = (q == 2) ?  2.f :  1.f;
  const float bb = (q == 2) ? -1.f :  0.f;

  __shared__ __align__(16) _Float16 h_sh[2][HID];

  float c = c0[(size_t)b * HID + j];
  if (q == 0) h_sh[0][j] = (_Float16)h0[(size_t)b * HID + j];
  __syncthreads();

  // xp: one fp16 per thread per step at [t][j*4+q] = [t][tid]
  const unsigned short* xps = (const unsigned short*)xp;
  const size_t xbase = (size_t)b * T * G4 + tid;
  unsigned short xv  = xps[xbase];
  unsigned short xv1 = (T > 1) ? xps[xbase + G4] : (unsigned short)0;

  const _Float16* rb = h_sh[0];
  _Float16*       wb = h_sh[1];

  for (int t = 0; t < T; ++t) {
    unsigned short xv2 = 0;
    if (t + 2 < T) xv2 = xps[xbase + (size_t)(t + 2) * G4];

    // my K-quarter of h: 4x ds_read_b128, all in flight
    uint4 hv0, hv1, hv2, hv3;
    {
      const uint4* h4 = (const uint4*)(rb + q * 32);
      hv0 = h4[0]; hv1 = h4[1]; hv2 = h4[2]; hv3 = h4[3];
    }

    float a0 = 0.f, a1 = 0.f, a2 = 0.f, a3 = 0.f;
#define DOTQ(vv, base)                                          \
    do {                                                        \
      a0 = fdot2(as_h2((vv).x), w0[(base) + 0], a0);            \
      a1 = fdot2(as_h2((vv).x), w1[(base) + 0], a1);            \
      a2 = fdot2(as_h2((vv).x), w2[(base) + 0], a2);            \
      a3 = fdot2(as_h2((vv).x), w3[(base) + 0], a3);            \
      a0 = fdot2(as_h2((vv).y), w0[(base) + 1], a0);            \
      a1 = fdot2(as_h2((vv).y), w1[(base) + 1], a1);            \
      a2 = fdot2(as_h2((vv).y), w2[(base) + 1], a2);            \
      a3 = fdot2(as_h2((vv).y), w3[(base) + 1], a3);            \
      a0 = fdot2(as_h2((vv).z), w0[(base) + 2], a0);            \
      a1 = fdot2(as_h2((vv).z), w1[(base) + 2], a1);            \
      a2 = fdot2(as_h2((vv).z), w2[(base) + 2], a2);            \
      a3 = fdot2(as_h2((vv).z), w3[(base) + 2], a3);            \
      a0 = fdot2(as_h2((vv).w), w0[(base) + 3], a0);            \
      a1 = fdot2(as_h2((vv).w), w1[(base) + 3], a1);            \
      a2 = fdot2(as_h2((vv).w), w2[(base) + 3], a2);            \
      a3 = fdot2(as_h2((vv).w), w3[(base) + 3], a3);            \
    } while (0)
    DOTQ(hv0, 0);
    DOTQ(hv1, 4);
    DOTQ(hv2, 8);
    DOTQ(hv3, 12);
#undef DOTQ

    // add x_proj: lane q carries gate q's xp (selector consts hoisted)
    {
      _Float16 xh = __builtin_bit_cast(_Float16, xv);
      float xvf = (float)xh;
      a0 = fmaf(xvf, s0, a0);
      a1 = fmaf(xvf, s1, a1);
      a2 = fmaf(xvf, s2, a2);
      a3 = fmaf(xvf, s3, a3);
    }

    // quad reduction over K-quarters (VALU-only)
    a0 = dpp_add<QP_XOR1>(a0); a0 = dpp_add<QP_XOR2>(a0);
    a1 = dpp_add<QP_XOR1>(a1); a1 = dpp_add<QP_XOR2>(a1);
    a2 = dpp_add<QP_XOR1>(a2); a2 = dpp_add<QP_XOR2>(a2);
    a3 = dpp_add<QP_XOR1>(a3); a3 = dpp_add<QP_XOR2>(a3);

    // own-gate select (2-bit mux) + branchless activation
    float a01 = (q & 1) ? a1 : a0;
    float a23 = (q & 1) ? a3 : a2;
    float aq  = (q & 2) ? a23 : a01;
    float act = fmaf(mm, __builtin_amdgcn_rcpf(1.0f + __expf(kk * aq)), bb);

    // regather i,f,g,o within the quad
    float gi = dpp_bcast<QP_B0>(act);
    float gf = dpp_bcast<QP_B1>(act);
    float gg = dpp_bcast<QP_B2>(act);
    float go = dpp_bcast<QP_B3>(act);

    c = fmaf(gf, c, gi * gg);            // replicated per quad (bit-identical)
    float h = go * tanhf_fast(c);

    if (q == 0) wb[j] = (_Float16)h;
    if (q == 1) out[((size_t)b * T + t) * HID + j] = h;
    barrier_lgkm();                      // single barrier, vmcnt not drained
    const _Float16* tmp = rb; rb = wb; wb = (_Float16*)tmp;
    xv = xv1; xv1 = xv2;
  }
}

// ---------------------------------------------------------------------------
// Fallback (ws too small): inline x-proj, round-1 structure.
// ---------------------------------------------------------------------------
__global__ __launch_bounds__(512, 2)
void lstm_scan_fb(const float* __restrict__ x, const float* __restrict__ Wih,
                  const float* __restrict__ Whh,
                  const float* __restrict__ bih, const float* __restrict__ bhh,
                  const float* __restrict__ h0, const float* __restrict__ c0,
                  float* __restrict__ out, int T)
{
  const int g = threadIdx.x;
  const int b = blockIdx.x;

  half2f w[64];
  {
    const float4* wr = (const float4*)(Whh + (size_t)g * HID);
#pragma unroll
    for (int q = 0; q < 32; q++) {
      float4 v = wr[q];
      w[2 * q + 0] = mk2(v.x, v.y);
      w[2 * q + 1] = mk2(v.z, v.w);
    }
  }
  half2f wi[32];
  float bias;
  {
    const float4* wr = (const float4*)(Wih + (size_t)g * DIN);
#pragma unroll
    for (int q = 0; q < 16; q++) {
      float4 v = wr[q];
      wi[2 * q + 0] = mk2(v.x, v.y);
      wi[2 * q + 1] = mk2(v.z, v.w);
    }
    bias = bih[g] + bhh[g];
  }

  __shared__ __align__(16) _Float16 h_sh[HID];
  __shared__ __align__(16) _Float16 xin[DIN];
  __shared__ float pre[G4];

  float c = 0.f;
  if (g < HID) {
    c = c0[(size_t)b * HID + g];
    h_sh[g] = (_Float16)h0[(size_t)b * HID + g];
  }
  if (g < DIN) xin[g] = (_Float16)x[((size_t)b * T) * DIN + g];
  __syncthreads();

  const bool is_tanh_gate = (g >= 2 * HID) && (g < 3 * HID);

  for (int t = 0; t < T; ++t) {
    float a[4] = {0.f, 0.f, 0.f, 0.f};
    const uint4* h4 = (const uint4*)h_sh;
#pragma unroll
    for (int q = 0; q < 16; q++) {
      uint4 hv = h4[q];
      a[q & 3] = fdot2(as_h2(hv.x), w[4 * q + 0], a[q & 3]);
      a[q & 3] = fdot2(as_h2(hv.y), w[4 * q + 1], a[q & 3]);
      a[q & 3] = fdot2(as_h2(hv.z), w[4 * q + 2], a[q & 3]);
      a[q & 3] = fdot2(as_h2(hv.w), w[4 * q + 3], a[q & 3]);
    }
    const uint4* x4 = (const uint4*)xin;
#pragma unroll
    for (int q = 0; q < 8; q++) {
      uint4 hv = x4[q];
      a[q & 3] = fdot2(as_h2(hv.x), wi[4 * q + 0], a[q & 3]);
      a[q & 3] = fdot2(as_h2(hv.y), wi[4 * q + 1], a[q & 3]);
      a[q & 3] = fdot2(as_h2(hv.z), wi[4 * q + 2], a[q & 3]);
      a[q & 3] = fdot2(as_h2(hv.w), wi[4 * q + 3], a[q & 3]);
    }
    float preact = a[0] + a[1] + a[2] + a[3] + bias;
    float act = is_tanh_gate ? tanhf_fast(preact) : sigmoidf_fast(preact);
    pre[g] = act;
    __syncthreads();

    if (g < HID) {
      float i  = pre[g];
      float f  = pre[g + HID];
      float gg = pre[g + 2 * HID];
      float o  = pre[g + 3 * HID];
      c = f * c + i * gg;
      float h = o * tanhf_fast(c);
      out[((size_t)b * T + t) * HID + g] = h;
      h_sh[g] = (_Float16)h;
    } else if (g >= HID && g < HID + DIN) {
      int d = g - HID;
      if (t + 1 < T) xin[d] = (_Float16)x[((size_t)b * T + (t + 1)) * DIN + d];
    }
    __syncthreads();
  }
}

// ---------------------------------------------------------------------------
extern "C" void kernel_launch(void* const* d_in, const int* in_sizes, int n_in,
                              void* d_out, int out_size, void* d_ws, size_t ws_size,
                              hipStream_t stream)
{
  const float* x   = (const float*)d_in[0];
  const float* Wih = (const float*)d_in[1];
  const float* Whh = (const float*)d_in[2];
  const float* bih = (const float*)d_in[3];
  const float* bhh = (const float*)d_in[4];
  const float* h0  = (const float*)d_in[5];
  const float* c0  = (const float*)d_in[6];
  float* out = (float*)d_out;

  const int B = in_sizes[5] / HID;
  const int T = in_sizes[0] / (B * DIN);
  const int nrows = B * T;

  const size_t xp_bytes = (size_t)nrows * G4 * sizeof(_Float16);
  if (ws_size >= xp_bytes) {
    _Float16* xp = (_Float16*)d_ws;
    xproj_kernel<<<1024, 512, 0, stream>>>(x, Wih, bih, bhh, xp, nrows);
    lstm_scan9<<<B, 512, 0, stream>>>(Whh, h0, c0, xp, out, T);
  } else {
    lstm_scan_fb<<<B, 512, 0, stream>>>(x, Wih, Whh, bih, bhh, h0, c0, out, T);
  }
}